// Round 1
// baseline (84.414 us; speedup 1.0000x reference)
//
#include <hip/hip_runtime.h>
#include <hip/hip_bf16.h>

#define B_ROWS 4096
#define DD 256
#define NN 8192
#define CHUNKS 8
#define CHUNK_COLS (NN / CHUNKS)   // 1024
#define ROWS_PER_BLOCK 128
#define TILE_COLS 64

typedef __attribute__((ext_vector_type(8))) short bf16x8;
typedef __attribute__((ext_vector_type(4))) float f32x4;

__device__ __forceinline__ unsigned short f2bf(float f) {
    unsigned int x = __float_as_uint(f);
    x += 0x7fffu + ((x >> 16) & 1u);   // RNE
    return (unsigned short)(x >> 16);
}

// ---------------- Kernel 1: cast z = [z_i; z_j] to bf16 in ws ----------------
__global__ void cast_kernel(const float* __restrict__ zi, const float* __restrict__ zj,
                            unsigned short* __restrict__ zb) {
    const int t = blockIdx.x * blockDim.x + threadIdx.x;      // 0 .. NN*DD/4-1
    const int half = B_ROWS * DD / 4;                          // 262144
    float4 v = (t < half) ? ((const float4*)zi)[t] : ((const float4*)zj)[t - half];
    ushort4 o;
    o.x = f2bf(v.x); o.y = f2bf(v.y); o.z = f2bf(v.z); o.w = f2bf(v.w);
    ((ushort4*)zb)[t] = o;
}

// ---------------- Kernel 2: pos_r = 2 * dot(z_i[r], z_j[r]) in fp32 ----------
__global__ void pos_kernel(const float* __restrict__ zi, const float* __restrict__ zj,
                           float* __restrict__ pos) {
    const int w = threadIdx.x >> 6;
    const int l = threadIdx.x & 63;
    const int r = blockIdx.x * 4 + w;                          // grid 1024 -> r < 4096
    const float4 a = ((const float4*)(zi + r * DD))[l];
    const float4 b = ((const float4*)(zj + r * DD))[l];
    float d = a.x * b.x + a.y * b.y + a.z * b.z + a.w * b.w;
    #pragma unroll
    for (int off = 32; off > 0; off >>= 1) d += __shfl_down(d, off, 64);
    if (l == 0) pos[r] = 2.0f * d;
}

// ---------------- Kernel 3: Gram MFMA + online row softmax stats -------------
// grid: 512 blocks = 64 row-groups (128 rows) x 8 column chunks (1024 cols)
// block: 512 threads = 8 waves, wave w owns rows r0 = rb + 16w .. +16
__global__ __launch_bounds__(512, 4) void simlse_kernel(const unsigned short* __restrict__ zb,
                                                        float* __restrict__ pm,
                                                        float* __restrict__ ps) {
    __shared__ unsigned short tile[TILE_COLS * DD];            // 32 KB
    const int tid = threadIdx.x;
    const int w   = tid >> 6;
    const int l   = tid & 63;
    const int lg  = l >> 4;         // 0..3
    const int lr  = l & 15;         // 0..15
    const int bid = blockIdx.x;
    const int rb  = (bid >> 3) * ROWS_PER_BLOCK;
    const int cc  = bid & 7;
    const int col_base = cc * CHUNK_COLS;
    const int r0  = rb + w * 16;

    // A fragments: lane holds rows r0+lr, k = ks*32 + lg*8 .. +8 (consecutive)
    bf16x8 aF[8];
    const unsigned short* ap = zb + (r0 + lr) * DD + lg * 8;
    #pragma unroll
    for (int ks = 0; ks < 8; ++ks) aF[ks] = *(const bf16x8*)(ap + ks * 32);

    // per-lane online stats for rows r0 + lg*4 + j (this lane's column slice)
    float m2[4] = {-1e30f, -1e30f, -1e30f, -1e30f};
    float s2[4] = {0.f, 0.f, 0.f, 0.f};

    for (int t = 0; t < CHUNK_COLS / TILE_COLS; ++t) {
        const int c0 = col_base + t * TILE_COLS;
        __syncthreads();                                        // prev tile fully consumed
        // stage 64 cols x 256 k (bf16), XOR-swizzled rows to kill bank conflicts
        #pragma unroll
        for (int j = 0; j < 4; ++j) {
            const int ch  = tid + j * 512;                      // 16B chunk id, 0..2047
            const int row = ch >> 5;
            const int k16 = ch & 31;
            int byte = row * 512 + k16 * 16;
            byte ^= (row & 7) << 4;
            *(bf16x8*)((char*)tile + byte) =
                *(const bf16x8*)(zb + (c0 + row) * DD + k16 * 8);
        }
        __syncthreads();
        #pragma unroll
        for (int s = 0; s < 4; ++s) {
            const int bcol = s * 16 + lr;                       // LDS row for B frag
            const int gc   = c0 + bcol;                         // global column
            f32x4 acc = {0.f, 0.f, 0.f, 0.f};
            #pragma unroll
            for (int ks = 0; ks < 8; ++ks) {
                int byte = bcol * 512 + ks * 64 + lg * 16;
                byte ^= (bcol & 7) << 4;
                bf16x8 bF = *(const bf16x8*)((char*)tile + byte);
                acc = __builtin_amdgcn_mfma_f32_16x16x32_bf16(aF[ks], bF, acc, 0, 0, 0);
            }
            #pragma unroll
            for (int j = 0; j < 4; ++j) {
                const int grow = r0 + lg * 4 + j;               // C/D: row=(lane>>4)*4+reg
                float v = acc[j] * 2.0f;                        // 1/TEMP
                if (grow == gc) v = -1e30f;                     // mask diagonal
                if (v > m2[j]) { s2[j] *= __expf(m2[j] - v); m2[j] = v; }
                s2[j] += __expf(v - m2[j]);
            }
        }
    }

    // merge the 16 column-slices (lanes sharing lg) per row, write chunk partial
    #pragma unroll
    for (int j = 0; j < 4; ++j) {
        #pragma unroll
        for (int d = 1; d < 16; d <<= 1) {
            float om = __shfl_xor(m2[j], d, 64);
            float os = __shfl_xor(s2[j], d, 64);
            float M  = fmaxf(m2[j], om);
            s2[j] = s2[j] * __expf(m2[j] - M) + os * __expf(om - M);
            m2[j] = M;
        }
        if (lr == 0) {
            const int row = r0 + lg * 4 + j;
            pm[row * CHUNKS + cc] = m2[j];
            ps[row * CHUNKS + cc] = s2[j];
        }
    }
}

// ---------------- Kernel 4: deterministic merge + final scalar ---------------
__global__ void finalize_kernel(const float* __restrict__ pm, const float* __restrict__ ps,
                                const float* __restrict__ pos, float* __restrict__ out) {
    __shared__ float red[256];
    const int tid = threadIdx.x;
    float local = 0.f;
    for (int r = tid; r < NN; r += 256) {
        float M = -1e30f;
        #pragma unroll
        for (int c = 0; c < CHUNKS; ++c) M = fmaxf(M, pm[r * CHUNKS + c]);
        float S = 0.f;
        #pragma unroll
        for (int c = 0; c < CHUNKS; ++c) S += ps[r * CHUNKS + c] * __expf(pm[r * CHUNKS + c] - M);
        local += M + logf(S);
    }
    for (int r = tid; r < B_ROWS; r += 256) local -= 2.0f * pos[r];
    red[tid] = local;
    __syncthreads();
    for (int st = 128; st > 0; st >>= 1) {
        if (tid < st) red[tid] += red[tid + st];
        __syncthreads();
    }
    if (tid == 0) out[0] = red[0] / (8192.f * 8192.f);
}

extern "C" void kernel_launch(void* const* d_in, const int* in_sizes, int n_in,
                              void* d_out, int out_size, void* d_ws, size_t ws_size,
                              hipStream_t stream) {
    const float* zi = (const float*)d_in[0];
    const float* zj = (const float*)d_in[1];
    float* out = (float*)d_out;
    char* ws = (char*)d_ws;

    unsigned short* zb = (unsigned short*)ws;                  // NN*DD*2   = 4 MB
    float* pm  = (float*)(ws + (size_t)NN * DD * 2);           // NN*CHUNKS = 256 KB
    float* ps  = pm + NN * CHUNKS;                             // 256 KB
    float* pos = ps + NN * CHUNKS;                             // 16 KB

    hipLaunchKernelGGL(cast_kernel,     dim3(NN * DD / 4 / 256), dim3(256), 0, stream, zi, zj, zb);
    hipLaunchKernelGGL(pos_kernel,      dim3(B_ROWS / 4),        dim3(256), 0, stream, zi, zj, pos);
    hipLaunchKernelGGL(simlse_kernel,   dim3((NN / ROWS_PER_BLOCK) * CHUNKS), dim3(512), 0, stream, zb, pm, ps);
    hipLaunchKernelGGL(finalize_kernel, dim3(1),                 dim3(256), 0, stream, pm, ps, pos, out);
}

// Round 2
// 69.974 us; speedup vs baseline: 1.2064x; 1.2064x over previous
//
#include <hip/hip_runtime.h>
#include <hip/hip_bf16.h>

#define B_ROWS 4096
#define DD 256
#define NN 8192
#define CHUNKS 16
#define CHUNK_COLS (NN / CHUNKS)       // 512
#define ROWS_PER_BLOCK 128
#define TILE_COLS 64
#define SCALE 1.6986436f               // sqrt(2*log2(e)) -> sim lands in exp2 domain
#define LN2 0.69314718f

typedef __attribute__((ext_vector_type(8))) short bf16x8;
typedef __attribute__((ext_vector_type(4))) float f32x4;

__device__ __forceinline__ unsigned short f2bf(float f) {
    unsigned int x = __float_as_uint(f);
    x += 0x7fffu + ((x >> 16) & 1u);   // RNE
    return (unsigned short)(x >> 16);
}
__device__ __forceinline__ float exp2_raw(float x) {
    float r; asm("v_exp_f32 %0, %1" : "=v"(r) : "v"(x)); return r;
}
__device__ __forceinline__ void gload16(const unsigned short* g, unsigned short* l) {
    __builtin_amdgcn_global_load_lds(
        (const __attribute__((address_space(1))) void*)g,
        (__attribute__((address_space(3))) void*)l, 16, 0, 0);
}

// ------------- Kernel 1: fused cast(z*SCALE -> bf16) + pos dot (fp32) --------
__global__ void cast_pos_kernel(const float* __restrict__ zi, const float* __restrict__ zj,
                                unsigned short* __restrict__ zb, float* __restrict__ pos) {
    const int w = threadIdx.x >> 6;
    const int l = threadIdx.x & 63;
    const int r = blockIdx.x * 4 + w;                       // grid 1024 -> r < 4096
    const float4 a = ((const float4*)(zi + (size_t)r * DD))[l];
    const float4 b = ((const float4*)(zj + (size_t)r * DD))[l];
    float d = a.x * b.x + a.y * b.y + a.z * b.z + a.w * b.w;
    #pragma unroll
    for (int off = 32; off > 0; off >>= 1) d += __shfl_down(d, off, 64);
    if (l == 0) pos[r] = 2.0f * d;                          // natural-domain sim value
    ushort4 oa, ob;
    oa.x = f2bf(a.x * SCALE); oa.y = f2bf(a.y * SCALE);
    oa.z = f2bf(a.z * SCALE); oa.w = f2bf(a.w * SCALE);
    ob.x = f2bf(b.x * SCALE); ob.y = f2bf(b.y * SCALE);
    ob.z = f2bf(b.z * SCALE); ob.w = f2bf(b.w * SCALE);
    ((ushort4*)(zb + (size_t)r * DD))[l] = oa;
    ((ushort4*)(zb + (size_t)(r + B_ROWS) * DD))[l] = ob;
}

// ------------- Kernel 2: Gram MFMA + online row softmax stats ----------------
// grid: 1024 = 64 row-groups (128 rows) x 16 column chunks (512 cols)
// LDS tile in MFMA-fragment order: block (s,ks) at (s*8+ks)*1024 bytes,
// lane-linear 16B slots -> conflict-free ds_read_b128 with immediate offsets.
__global__ __launch_bounds__(512, 8) void simlse_kernel(const unsigned short* __restrict__ zb,
                                                        float* __restrict__ pm,
                                                        float* __restrict__ ps) {
    __shared__ unsigned short tile[TILE_COLS * DD];         // 32 KB
    const int tid = threadIdx.x;
    const int w   = tid >> 6;           // wave 0..7  (doubles as ks for staging)
    const int l   = tid & 63;
    const int lg  = l >> 4;             // 0..3
    const int lr  = l & 15;             // 0..15
    const int bid = blockIdx.x;
    const int rb  = (bid >> 4) * ROWS_PER_BLOCK;
    const int cc  = bid & 15;
    const int col_base = cc * CHUNK_COLS;
    const int r0  = rb + w * 16;

    // A fragments: lane holds row r0+lr, k = ks*32 + lg*8 .. +8
    bf16x8 aF[8];
    const unsigned short* ap = zb + (size_t)(r0 + lr) * DD + lg * 8;
    #pragma unroll
    for (int ks = 0; ks < 8; ++ks) aF[ks] = *(const bf16x8*)(ap + ks * 32);

    float m2[4] = {-1e30f, -1e30f, -1e30f, -1e30f};
    float s2[4] = {0.f, 0.f, 0.f, 0.f};

    // per-lane gather source: col = col_base + j*16 + lr, k16 = w*4 + lg
    const unsigned short* gp = zb + (size_t)(col_base + lr) * DD + w * 32 + lg * 8;
    unsigned short* lbase = tile + w * 512;                 // + j*4096 per j
    const unsigned short* bptr = tile + l * 8;              // lane-linear frag reads

    for (int t = 0; t < CHUNK_COLS / TILE_COLS; ++t) {
        __syncthreads();                                    // prev tile consumed
        #pragma unroll
        for (int j = 0; j < 4; ++j)
            gload16(gp + t * (TILE_COLS * DD) + j * (16 * DD), lbase + j * 4096);
        __syncthreads();                                    // vmcnt(0) drain + barrier
        const int c0 = col_base + t * TILE_COLS;
        #pragma unroll
        for (int s = 0; s < 4; ++s) {
            f32x4 acc = {0.f, 0.f, 0.f, 0.f};
            #pragma unroll
            for (int ks = 0; ks < 8; ++ks) {
                bf16x8 bF = *(const bf16x8*)(bptr + s * 4096 + ks * 512);
                acc = __builtin_amdgcn_mfma_f32_16x16x32_bf16(aF[ks], bF, acc, 0, 0, 0);
            }
            if (c0 + s * 16 == r0) {                        // wave-uniform diag tile
                #pragma unroll
                for (int j = 0; j < 4; ++j)
                    if (lr == lg * 4 + j) acc[j] = -__builtin_inff();
            }
            #pragma unroll
            for (int j = 0; j < 4; ++j) {
                float v = acc[j];
                if (v > m2[j]) { s2[j] *= exp2_raw(m2[j] - v); m2[j] = v; }
                s2[j] += exp2_raw(v - m2[j]);
            }
        }
    }

    // merge 16 column-slices (lanes sharing lg) per row; write chunk partials
    #pragma unroll
    for (int j = 0; j < 4; ++j) {
        #pragma unroll
        for (int d = 1; d < 16; d <<= 1) {
            float om = __shfl_xor(m2[j], d, 64);
            float os = __shfl_xor(s2[j], d, 64);
            float M  = fmaxf(m2[j], om);
            s2[j] = s2[j] * exp2_raw(m2[j] - M) + os * exp2_raw(om - M);
            m2[j] = M;
        }
        if (lr == 0) {
            const int row = r0 + lg * 4 + j;
            pm[row * CHUNKS + cc] = m2[j];
            ps[row * CHUNKS + cc] = s2[j];
        }
    }
}

// ------------- Kernel 3: per-row merge of 16 partials + pos subtraction ------
__global__ void rowmerge_kernel(const float* __restrict__ pm, const float* __restrict__ ps,
                                const float* __restrict__ pos, float* __restrict__ partial) {
    const int r = blockIdx.x * 256 + threadIdx.x;           // grid 32 -> r < 8192
    float M = -1e30f;
    #pragma unroll
    for (int c = 0; c < CHUNKS; ++c) M = fmaxf(M, pm[r * CHUNKS + c]);
    float S = 0.f;
    #pragma unroll
    for (int c = 0; c < CHUNKS; ++c) S += ps[r * CHUNKS + c] * exp2_raw(pm[r * CHUNKS + c] - M);
    float val = M * LN2 + logf(S);                          // back to natural log
    if (r < B_ROWS) val -= 2.0f * pos[r];
    __shared__ float red[256];
    red[threadIdx.x] = val;
    __syncthreads();
    for (int st = 128; st > 0; st >>= 1) {
        if (threadIdx.x < st) red[threadIdx.x] += red[threadIdx.x + st];
        __syncthreads();
    }
    if (threadIdx.x == 0) partial[blockIdx.x] = red[0];
}

// ------------- Kernel 4: final scalar ----------------------------------------
__global__ void final_kernel(const float* __restrict__ partial, float* __restrict__ out) {
    float v = (threadIdx.x < 32) ? partial[threadIdx.x] : 0.f;
    #pragma unroll
    for (int off = 32; off > 0; off >>= 1) v += __shfl_down(v, off, 64);
    if (threadIdx.x == 0) out[0] = v / (8192.f * 8192.f);
}

extern "C" void kernel_launch(void* const* d_in, const int* in_sizes, int n_in,
                              void* d_out, int out_size, void* d_ws, size_t ws_size,
                              hipStream_t stream) {
    const float* zi = (const float*)d_in[0];
    const float* zj = (const float*)d_in[1];
    float* out = (float*)d_out;
    char* ws = (char*)d_ws;

    unsigned short* zb = (unsigned short*)ws;               // 4 MB
    float* pm      = (float*)(ws + (size_t)NN * DD * 2);    // 512 KB
    float* ps      = pm + NN * CHUNKS;                      // 512 KB
    float* pos     = ps + NN * CHUNKS;                      // 16 KB
    float* partial = pos + B_ROWS;                          // 128 B

    hipLaunchKernelGGL(cast_pos_kernel, dim3(B_ROWS / 4), dim3(256), 0, stream, zi, zj, zb, pos);
    hipLaunchKernelGGL(simlse_kernel,   dim3((NN / ROWS_PER_BLOCK) * CHUNKS), dim3(512), 0, stream, zb, pm, ps);
    hipLaunchKernelGGL(rowmerge_kernel, dim3(NN / 256), dim3(256), 0, stream, pm, ps, pos, partial);
    hipLaunchKernelGGL(final_kernel,    dim3(1), dim3(64), 0, stream, partial, out);
}

// Round 3
// 66.429 us; speedup vs baseline: 1.2707x; 1.0534x over previous
//
#include <hip/hip_runtime.h>
#include <hip/hip_bf16.h>

#define DD 256
#define NN 8192
#define B_ROWS 4096
#define G 64                   // row/col groups of 128
#define NPAIRS 2080            // G*(G+1)/2
#define M_FIX 160.0f           // fixed softmax offset (exp2 domain)
#define SCALE 1.6986436f       // sqrt(2*log2(e)): sim lands in exp2 domain
#define LN2 0.69314718055994531f

typedef __attribute__((ext_vector_type(8))) short bf16x8;
typedef __attribute__((ext_vector_type(4))) float f32x4;

__device__ __forceinline__ unsigned short f2bf(float f) {
    unsigned int x = __float_as_uint(f);
    x += 0x7fffu + ((x >> 16) & 1u);   // RNE
    return (unsigned short)(x >> 16);
}
__device__ __forceinline__ float bf2f(unsigned short u) {
    return __uint_as_float((unsigned int)u << 16);
}
__device__ __forceinline__ float exp2_raw(float x) {
    float r; asm("v_exp_f32 %0, %1" : "=v"(r) : "v"(x)); return r;
}
__device__ __forceinline__ void gload16(const unsigned short* g, unsigned short* l) {
    __builtin_amdgcn_global_load_lds(
        (const __attribute__((address_space(1))) void*)g,
        (__attribute__((address_space(3))) void*)l, 16, 0, 0);
}

// ------------- Kernel 1: fused cast(z*SCALE -> bf16) + pos dot (fp32) --------
__global__ void cast_pos_kernel(const float* __restrict__ zi, const float* __restrict__ zj,
                                unsigned short* __restrict__ zb, float* __restrict__ pos) {
    const int w = threadIdx.x >> 6;
    const int l = threadIdx.x & 63;
    const int r = blockIdx.x * 4 + w;                       // grid 1024 -> r < 4096
    const float4 a = ((const float4*)(zi + (size_t)r * DD))[l];
    const float4 b = ((const float4*)(zj + (size_t)r * DD))[l];
    float d = a.x * b.x + a.y * b.y + a.z * b.z + a.w * b.w;
    #pragma unroll
    for (int off = 32; off > 0; off >>= 1) d += __shfl_down(d, off, 64);
    if (l == 0) pos[r] = 2.0f * d;                          // natural-domain pos value
    ushort4 oa, ob;
    oa.x = f2bf(a.x * SCALE); oa.y = f2bf(a.y * SCALE);
    oa.z = f2bf(a.z * SCALE); oa.w = f2bf(a.w * SCALE);
    ob.x = f2bf(b.x * SCALE); ob.y = f2bf(b.y * SCALE);
    ob.z = f2bf(b.z * SCALE); ob.w = f2bf(b.w * SCALE);
    ((ushort4*)(zb + (size_t)r * DD))[l] = oa;
    ((ushort4*)(zb + (size_t)(r + B_ROWS) * DD))[l] = ob;
}

// ------------- Kernel 2: symmetric Gram + fixed-M exp2 sums ------------------
// grid: 2080 blocks = pairs (g1<=g2) of 128-row groups. block: 128 thr = 2 waves.
// Wave owns 64 rows (4 row-tiles of 16) in registers; B staged 64 cols x 256 K
// in LDS fragment order; each bF read feeds 4 MFMAs (R=4 reuse).
// Off-diagonal blocks also accumulate column sums (mirror half, by symmetry).
__global__ __launch_bounds__(128, 2) void simlse_kernel(const unsigned short* __restrict__ zb,
                                                        unsigned short* __restrict__ P) {
    __shared__ unsigned short tile[64 * DD];                // 32 KB
    const int tid = threadIdx.x;
    const int w  = tid >> 6;
    const int l  = tid & 63;
    const int lg = l >> 4;          // 0..3
    const int lr = l & 15;          // 0..15

    int b = blockIdx.x, g1 = 0;
    while (b >= G - g1) { b -= G - g1; ++g1; }
    const int g2 = g1 + b;
    const int rbase = g1 * 128 + w * 64;
    const int cbase = g2 * 128;
    const bool diag = (g1 == g2);

    // A fragments: 4 row-tiles x 8 k-slices, 128 VGPR
    bf16x8 aF[4][8];
    #pragma unroll
    for (int rt = 0; rt < 4; ++rt) {
        const unsigned short* ap = zb + (size_t)(rbase + rt * 16 + lr) * DD + lg * 8;
        #pragma unroll
        for (int ks = 0; ks < 8; ++ks) aF[rt][ks] = *(const bf16x8*)(ap + ks * 32);
    }

    float rs[4][4];
    #pragma unroll
    for (int rt = 0; rt < 4; ++rt)
        #pragma unroll
        for (int j = 0; j < 4; ++j) rs[rt][j] = 0.f;
    float cs[8];
    #pragma unroll
    for (int k = 0; k < 8; ++k) cs[k] = 0.f;

    #pragma unroll
    for (int t = 0; t < 2; ++t) {
        const int c0 = cbase + t * 64;
        __syncthreads();                                    // prev tile consumed
        #pragma unroll
        for (int j = 0; j < 16; ++j) {                      // wave stages 16 slots
            const int slot = w * 16 + j;
            const int s = slot >> 3, ks = slot & 7;
            gload16(zb + (size_t)(c0 + s * 16 + lr) * DD + ks * 32 + lg * 8,
                    tile + slot * 512);
        }
        __syncthreads();
        #pragma unroll
        for (int s = 0; s < 4; ++s) {
            f32x4 acc[4];
            #pragma unroll
            for (int rt = 0; rt < 4; ++rt) acc[rt] = (f32x4){0.f, 0.f, 0.f, 0.f};
            #pragma unroll
            for (int ks = 0; ks < 8; ++ks) {
                bf16x8 bF = *(const bf16x8*)(tile + (s * 8 + ks) * 512 + l * 8);
                #pragma unroll
                for (int rt = 0; rt < 4; ++rt)
                    acc[rt] = __builtin_amdgcn_mfma_f32_16x16x32_bf16(aF[rt][ks], bF, acc[rt], 0, 0, 0);
            }
            float csum = 0.f;
            #pragma unroll
            for (int rt = 0; rt < 4; ++rt) {
                const bool dtile = diag && (w * 4 + rt == t * 4 + s);
                #pragma unroll
                for (int j = 0; j < 4; ++j) {
                    float e = exp2_raw(acc[rt][j] - M_FIX);
                    if (dtile && (lr == lg * 4 + j)) e = 0.f;   // mask i==j
                    rs[rt][j] += e;
                    csum += e;
                }
            }
            cs[t * 4 + s] = csum;
        }
    }

    // row sums: reduce across the 16 lanes sharing lg; lanes lr==0 write
    #pragma unroll
    for (int rt = 0; rt < 4; ++rt)
        #pragma unroll
        for (int j = 0; j < 4; ++j) {
            float v = rs[rt][j];
            v += __shfl_xor(v, 1, 64);
            v += __shfl_xor(v, 2, 64);
            v += __shfl_xor(v, 4, 64);
            v += __shfl_xor(v, 8, 64);
            rs[rt][j] = v;
        }
    if (lr == 0) {
        #pragma unroll
        for (int rt = 0; rt < 4; ++rt)
            #pragma unroll
            for (int j = 0; j < 4; ++j) {
                const int row = rbase + rt * 16 + lg * 4 + j;
                P[(size_t)row * G + g2] = f2bf(rs[rt][j]);
            }
    }

    // column sums (mirror half) — off-diagonal blocks only
    if (!diag) {
        #pragma unroll
        for (int k = 0; k < 8; ++k) {
            float v = cs[k];
            v += __shfl_xor(v, 16, 64);
            v += __shfl_xor(v, 32, 64);
            cs[k] = v;
        }
        __syncthreads();                                    // tile reads done; reuse as scratch
        float* red = (float*)tile;                          // [2][8][16]
        if (lg == 0) {
            #pragma unroll
            for (int k = 0; k < 8; ++k) red[(w * 8 + k) * 16 + lr] = cs[k];
        }
        __syncthreads();
        const int k2 = tid >> 4, lr2 = tid & 15;            // tid = k2*16+lr2 < 128
        float v = red[k2 * 16 + lr2] + red[(8 + k2) * 16 + lr2];
        P[(size_t)(cbase + tid) * G + g1] = f2bf(v);        // col = cbase + k2*16 + lr2
    }
}

// ------------- Kernel 3: per-row sum of 64 partials + pos subtraction --------
__global__ void rowmerge_kernel(const unsigned short* __restrict__ P,
                                const float* __restrict__ pos, float* __restrict__ partial) {
    const int r = blockIdx.x * 256 + threadIdx.x;           // grid 32 -> r < 8192
    float S = 0.f;
    const ushort4* p4 = (const ushort4*)(P + (size_t)r * G);
    #pragma unroll
    for (int k = 0; k < 16; ++k) {
        ushort4 u = p4[k];
        S += bf2f(u.x) + bf2f(u.y) + bf2f(u.z) + bf2f(u.w);
    }
    float val = M_FIX * LN2 + logf(S);                      // natural-domain lse
    if (r < B_ROWS) val -= 2.0f * pos[r];
    __shared__ float red[256];
    red[threadIdx.x] = val;
    __syncthreads();
    for (int st = 128; st > 0; st >>= 1) {
        if (threadIdx.x < st) red[threadIdx.x] += red[threadIdx.x + st];
        __syncthreads();
    }
    if (threadIdx.x == 0) partial[blockIdx.x] = red[0];
}

// ------------- Kernel 4: final scalar ----------------------------------------
__global__ void final_kernel(const float* __restrict__ partial, float* __restrict__ out) {
    float v = (threadIdx.x < 32) ? partial[threadIdx.x] : 0.f;
    #pragma unroll
    for (int off = 32; off > 0; off >>= 1) v += __shfl_down(v, off, 64);
    if (threadIdx.x == 0) out[0] = v / (8192.f * 8192.f);
}

extern "C" void kernel_launch(void* const* d_in, const int* in_sizes, int n_in,
                              void* d_out, int out_size, void* d_ws, size_t ws_size,
                              hipStream_t stream) {
    const float* zi = (const float*)d_in[0];
    const float* zj = (const float*)d_in[1];
    float* out = (float*)d_out;
    char* ws = (char*)d_ws;

    unsigned short* zb = (unsigned short*)ws;                    // 4 MB
    unsigned short* P  = (unsigned short*)(ws + (size_t)NN * DD * 2);  // 1 MB bf16 [8192][64]
    float* pos     = (float*)(ws + (size_t)NN * DD * 2 + (size_t)NN * G * 2);  // 16 KB
    float* partial = pos + B_ROWS;                               // 128 B

    hipLaunchKernelGGL(cast_pos_kernel, dim3(B_ROWS / 4), dim3(256), 0, stream, zi, zj, zb, pos);
    hipLaunchKernelGGL(simlse_kernel,   dim3(NPAIRS), dim3(128), 0, stream, zb, P);
    hipLaunchKernelGGL(rowmerge_kernel, dim3(NN / 256), dim3(256), 0, stream, P, pos, partial);
    hipLaunchKernelGGL(final_kernel,    dim3(1), dim3(64), 0, stream, partial, out);
}

// Round 5
// 56.787 us; speedup vs baseline: 1.4865x; 1.1698x over previous
//
#include <hip/hip_runtime.h>
#include <hip/hip_bf16.h>

#define DD 256
#define NN 8192
#define B_ROWS 4096
#define G 32                   // groups of 256 rows/cols
#define GSZ 256
#define NPAIRS 528             // G*(G+1)/2
#define M_FIX 160.0f           // fixed softmax offset (exp2 domain)
#define SCALE 1.6986436f       // sqrt(2*log2(e)): sim lands in exp2 domain
#define LN2 0.69314718055994531f

typedef __attribute__((ext_vector_type(8))) short bf16x8;
typedef __attribute__((ext_vector_type(4))) float f32x4;

__device__ __forceinline__ unsigned short f2bf(float f) {
    unsigned int x = __float_as_uint(f);
    x += 0x7fffu + ((x >> 16) & 1u);   // RNE
    return (unsigned short)(x >> 16);
}
__device__ __forceinline__ float bf2f(unsigned short u) {
    return __uint_as_float((unsigned int)u << 16);
}
__device__ __forceinline__ float exp2_raw(float x) {
    float r; asm("v_exp_f32 %0, %1" : "=v"(r) : "v"(x)); return r;
}
__device__ __forceinline__ void gload16(const unsigned short* g, unsigned short* l) {
    __builtin_amdgcn_global_load_lds(
        (const __attribute__((address_space(1))) void*)g,
        (__attribute__((address_space(3))) void*)l, 16, 0, 0);
}

// ------------- Kernel 1: fused cast(z*SCALE -> bf16) + pos dot (fp32) --------
__global__ void cast_pos_kernel(const float* __restrict__ zi, const float* __restrict__ zj,
                                unsigned short* __restrict__ zb, float* __restrict__ pos) {
    const int w = threadIdx.x >> 6;
    const int l = threadIdx.x & 63;
    const int r = blockIdx.x * 4 + w;                       // grid 1024 -> r < 4096
    const float4 a = ((const float4*)(zi + (size_t)r * DD))[l];
    const float4 b = ((const float4*)(zj + (size_t)r * DD))[l];
    float d = a.x * b.x + a.y * b.y + a.z * b.z + a.w * b.w;
    #pragma unroll
    for (int off = 32; off > 0; off >>= 1) d += __shfl_down(d, off, 64);
    if (l == 0) pos[r] = 2.0f * d;                          // natural-domain pos logit
    ushort4 oa, ob;
    oa.x = f2bf(a.x * SCALE); oa.y = f2bf(a.y * SCALE);
    oa.z = f2bf(a.z * SCALE); oa.w = f2bf(a.w * SCALE);
    ob.x = f2bf(b.x * SCALE); ob.y = f2bf(b.y * SCALE);
    ob.z = f2bf(b.z * SCALE); ob.w = f2bf(b.w * SCALE);
    ((ushort4*)(zb + (size_t)r * DD))[l] = oa;
    ((ushort4*)(zb + (size_t)(r + B_ROWS) * DD))[l] = ob;
}

// ------------- Kernel 2: symmetric Gram + fixed-M exp2 sums ------------------
// grid: 528 pair-blocks (g1<=g2) over 32 groups of 256. block: 256 thr = 4 waves.
// Wave w owns 64 rows (4 row-tiles, aF in 128 VGPR, R=4 reuse). Cols staged as
// 64-col single-buffered LDS tiles in MFMA fragment order (conflict-free);
// barrier pattern identical to the round-3-verified kernel.
// PT bf16 [G][NN]: row-sums at PT[g2][row], col-sums (mirror) at PT[g1][col].
__global__ __launch_bounds__(256, 2) void simlse_kernel(const unsigned short* __restrict__ zb,
                                                        unsigned short* __restrict__ PT) {
    __shared__ unsigned short tile[32 * 512];               // 32 KB: 64 cols x 256 K
    const int tid = threadIdx.x;
    const int w  = tid >> 6;        // 0..3
    const int l  = tid & 63;
    const int lg = l >> 4;          // 0..3
    const int lr = l & 15;          // 0..15

    int b = blockIdx.x, g1 = 0;
    while (b >= G - g1) { b -= G - g1; ++g1; }
    const int g2 = g1 + b;
    const bool diag = (g1 == g2);
    const int rbase = g1 * GSZ + w * 64;
    const int cbase = g2 * GSZ;

    // A fragments: 4 row-tiles x 8 k-slices (128 VGPR)
    bf16x8 aF[4][8];
    #pragma unroll
    for (int rt = 0; rt < 4; ++rt) {
        const unsigned short* ap = zb + (size_t)(rbase + rt * 16 + lr) * DD + lg * 8;
        #pragma unroll
        for (int ks = 0; ks < 8; ++ks) aF[rt][ks] = *(const bf16x8*)(ap + ks * 32);
    }

    float rs[4][4];
    #pragma unroll
    for (int rt = 0; rt < 4; ++rt)
        #pragma unroll
        for (int j = 0; j < 4; ++j) rs[rt][j] = 0.f;
    float cs[16];
    #pragma unroll
    for (int k = 0; k < 16; ++k) cs[k] = 0.f;

    for (int t = 0; t < 4; ++t) {
        const int c0 = cbase + t * 64;
        __syncthreads();                                    // prev tile fully consumed
        // wave w stages subtile s=w: 8 slots, lane-linear fragment order
        #pragma unroll
        for (int j = 0; j < 8; ++j)
            gload16(zb + (size_t)(c0 + w * 16 + lr) * DD + j * 32 + lg * 8,
                    tile + (w * 8 + j) * 512);
        __syncthreads();                                    // staging drained
        #pragma unroll
        for (int s = 0; s < 4; ++s) {
            const int ct = t * 4 + s;                       // col-tile idx, 0..15
            f32x4 acc[4];
            #pragma unroll
            for (int rt = 0; rt < 4; ++rt) acc[rt] = (f32x4){0.f, 0.f, 0.f, 0.f};
            #pragma unroll
            for (int ks = 0; ks < 8; ++ks) {
                bf16x8 bF = *(const bf16x8*)(tile + (s * 8 + ks) * 512 + l * 8);
                #pragma unroll
                for (int rt = 0; rt < 4; ++rt)
                    acc[rt] = __builtin_amdgcn_mfma_f32_16x16x32_bf16(aF[rt][ks], bF, acc[rt], 0, 0, 0);
            }
            #pragma unroll
            for (int rt = 0; rt < 4; ++rt) {
                const bool dt = diag && (w * 4 + rt == ct);
                #pragma unroll
                for (int j = 0; j < 4; ++j) {
                    float e = exp2_raw(acc[rt][j] - M_FIX);
                    if (dt && (lr == lg * 4 + j)) e = 0.f;  // mask i==j
                    rs[rt][j] += e;
                    cs[ct] += e;
                }
            }
        }
    }

    // row sums: reduce over the 16 lanes sharing lg; lr==0 lanes write
    #pragma unroll
    for (int rt = 0; rt < 4; ++rt)
        #pragma unroll
        for (int j = 0; j < 4; ++j) {
            float v = rs[rt][j];
            v += __shfl_xor(v, 1, 64);
            v += __shfl_xor(v, 2, 64);
            v += __shfl_xor(v, 4, 64);
            v += __shfl_xor(v, 8, 64);
            rs[rt][j] = v;
        }
    if (lr == 0) {
        #pragma unroll
        for (int rt = 0; rt < 4; ++rt)
            #pragma unroll
            for (int j = 0; j < 4; ++j)
                PT[(size_t)g2 * NN + rbase + rt * 16 + lg * 4 + j] = f2bf(rs[rt][j]);
    }

    // column sums (mirror half) — off-diagonal blocks only (block-uniform branch)
    if (!diag) {
        #pragma unroll
        for (int k = 0; k < 16; ++k) {
            float v = cs[k];
            v += __shfl_xor(v, 16, 64);
            v += __shfl_xor(v, 32, 64);
            cs[k] = v;                                      // sum over all 64 wave rows
        }
        __syncthreads();                                    // all tile READS done
        float* red = (float*)tile;                          // [4][256] floats = 4 KB
        if (lg == 0) {
            #pragma unroll
            for (int k = 0; k < 16; ++k) red[w * 256 + k * 16 + lr] = cs[k];
        }
        __syncthreads();
        const float v = red[tid] + red[256 + tid] + red[512 + tid] + red[768 + tid];
        PT[(size_t)g1 * NN + cbase + tid] = f2bf(v);        // col = cbase + tid
    }
}

// ------------- Kernel 3: per-row sum of 32 partials + pos subtraction --------
__global__ void rowmerge_kernel(const unsigned short* __restrict__ PT,
                                const float* __restrict__ pos, float* __restrict__ partial) {
    const int r = blockIdx.x * 256 + threadIdx.x;           // grid 32 -> r < 8192
    float S = 0.f;
    #pragma unroll
    for (int c = 0; c < G; ++c) S += bf2f(PT[(size_t)c * NN + r]);  // lane-coalesced
    float val = M_FIX * LN2 + logf(S);                      // natural-domain lse
    if (r < B_ROWS) val -= 2.0f * pos[r];                   // both halves' pos
    __shared__ float red[256];
    red[threadIdx.x] = val;
    __syncthreads();
    for (int st = 128; st > 0; st >>= 1) {
        if (threadIdx.x < st) red[threadIdx.x] += red[threadIdx.x + st];
        __syncthreads();
    }
    if (threadIdx.x == 0) partial[blockIdx.x] = red[0];
}

// ------------- Kernel 4: final scalar ----------------------------------------
__global__ void final_kernel(const float* __restrict__ partial, float* __restrict__ out) {
    float v = (threadIdx.x < 32) ? partial[threadIdx.x] : 0.f;
    #pragma unroll
    for (int off = 32; off > 0; off >>= 1) v += __shfl_down(v, off, 64);
    if (threadIdx.x == 0) out[0] = v / (8192.f * 8192.f);
}

extern "C" void kernel_launch(void* const* d_in, const int* in_sizes, int n_in,
                              void* d_out, int out_size, void* d_ws, size_t ws_size,
                              hipStream_t stream) {
    const float* zi = (const float*)d_in[0];
    const float* zj = (const float*)d_in[1];
    float* out = (float*)d_out;
    char* ws = (char*)d_ws;

    unsigned short* zb = (unsigned short*)ws;                         // 4 MB
    unsigned short* PT = (unsigned short*)(ws + (size_t)NN * DD * 2); // 512 KB bf16 [G][NN]
    float* pos     = (float*)(ws + (size_t)NN * DD * 2 + (size_t)G * NN * 2);  // 16 KB
    float* partial = pos + B_ROWS;                                    // 128 B

    hipLaunchKernelGGL(cast_pos_kernel, dim3(B_ROWS / 4), dim3(256), 0, stream, zi, zj, zb, pos);
    hipLaunchKernelGGL(simlse_kernel,   dim3(NPAIRS), dim3(256), 0, stream, zb, PT);
    hipLaunchKernelGGL(rowmerge_kernel, dim3(NN / 256), dim3(256), 0, stream, PT, pos, partial);
    hipLaunchKernelGGL(final_kernel,    dim3(1), dim3(64), 0, stream, partial, out);
}